// Round 18
// baseline (21.554 us; speedup 1.0000x reference)
//
#include <hip/hip_runtime.h>
#include <math.h>

#define NSPL 128
#define SCALE 512.0f

__device__ __forceinline__ float fast_cbrt_pos(float x) {
    // x >= 0. Bit-hack seed (no log/exp) + 2 rcp-Newton steps; rel err ~1e-5.
    unsigned int i = __float_as_uint(x);
    i = 0x2a510680u + (unsigned int)(((unsigned long long)i * 0xAAAAAAABull) >> 33);
    float r = __uint_as_float(i);
    float r2 = r * r;
    r = fmaf(0.66666667f, r, 0.33333333f * x * __builtin_amdgcn_rcpf(r2));
    r2 = r * r;
    r = fmaf(0.66666667f, r, 0.33333333f * x * __builtin_amdgcn_rcpf(r2));
    return (x < 1e-35f) ? 0.0f : r;
}

// Hastings deg-7 acos (abs err ~2e-8). Input here is EXACT (true divide +
// libm sqrt), so no input-side amplification (r2 post-mortem); output-side
// 2e-8 rad error shifts roots ~1e-8 -> invisible at bf16.
__device__ __forceinline__ float fast_acos(float x) {
    float ax = fabsf(x);
    float p = -0.0012624911f;
    p = fmaf(p, ax, 0.0066700901f);
    p = fmaf(p, ax, -0.0170881256f);
    p = fmaf(p, ax, 0.0308918810f);
    p = fmaf(p, ax, -0.0501743046f);
    p = fmaf(p, ax, 0.0889789874f);
    p = fmaf(p, ax, -0.2145988016f);
    p = fmaf(p, ax, 1.5707963050f);
    float s = __builtin_amdgcn_sqrtf(1.0f - ax);
    float r = s * p;
    return (x >= 0.0f) ? r : (3.14159265358979323846f - r);
}

// cos/sin on [0, pi/3] via Taylor-Horner (abs err <= 4e-8). r13-proven.
__device__ __forceinline__ float cos_small(float v) {
    const float v2 = v * v;
    float p = -2.7557319e-7f;
    p = fmaf(p, v2, 2.4801587e-5f);
    p = fmaf(p, v2, -1.3888889e-3f);
    p = fmaf(p, v2, 4.1666667e-2f);
    p = fmaf(p, v2, -0.5f);
    return fmaf(p, v2, 1.0f);
}
__device__ __forceinline__ float sin_small(float v) {
    const float v2 = v * v;
    float p = 2.7557319e-6f;
    p = fmaf(p, v2, -1.9841270e-4f);
    p = fmaf(p, v2, 8.3333333e-3f);
    p = fmaf(p, v2, -0.16666667f);
    return v * fmaf(p, v2, 1.0f);
}

// One kept-spline contribution for one pixel (r17 numerics + poly acos).
__device__ __forceinline__ float eval_one(
    float py, float px, const float4 f0, const float4 f1,
    const float4 f2, const float4 lw4)
{
    const float Ay = f0.z, Ax = f0.w;
    const float By = f1.x, Bx = f1.y;
    const float ca27 = f1.z, ca3 = f1.w;
    const float twoax2 = f2.x, third = f2.y, cbK = f2.z, r_nB = f2.w;

    const float Cy = py - f0.x, Cx = px - f0.y;
    const float CdB = Cy*By + Cx*Bx;
    const float CdA = Cy*Ay + Cx*Ax;
    const float cb = (CdB - cbK) * r_nB;
    const float cc = CdA * r_nB;

    const float p_  = cb - third;
    const float p3  = p_ * p_ * p_;
    const float q   = fmaf(ca27, fmaf(-9.0f, cb, twoax2), cc);
    const float d   = fmaf(q, q, p3 * (4.0f/27.0f));

    const bool sgl = d > 0.0f;
    // single-root via Cardano identity (r12-proven)
    const float sd = __builtin_amdgcn_sqrtf(fmaxf(d, 0.0f));
    const float mm = (fabsf(q) + sd) * 0.5f;
    const float r  = fast_cbrt_pos(mm);
    const float sg = (q > 0.0f) ? -1.0f : 1.0f;
    const float r0 = fmaf(sg, fmaf(-p_ * 0.33333334f, __builtin_amdgcn_rcpf(r), r), -ca3);

    float T0 = r0, T1 = r0;
    const unsigned long long bd = __ballot(sgl);
    if (bd != ~0ull) {  // trig branch: exact aarg (true div + libm sqrt)
        const float p3s = (fabsf(p3) > 1e-9f) ? p3 : 1e-9f;
        const float aarg = -sqrtf(fmaxf(-27.0f / p3s, 0.0f)) * q * 0.5f;
        const float v = fast_acos(fminf(fmaxf(aarg, -1.0f), 1.0f)) * (1.0f/3.0f);
        const float m = cos_small(v);
        const float nn = sin_small(v) * 1.7320508075688772f;
        const float sp = sqrtf(fmaxf(-p_ / 3.0f, 0.0f));
        const float r1 = (m + m) * sp - ca3;
        const float r2 = (-nn - m) * sp - ca3;
        if (!sgl) { T0 = r1; T1 = r2; }
    }
    T0 = fminf(fmaxf(T0, 0.0f), 1.0f);
    T1 = fminf(fmaxf(T1, 0.0f), 1.0f);

    const float Dy = Ay + Ay, Dx = Ax + Ax;
    const float d1y = (Dy + By*T0)*T0 - Cy, d1x = (Dx + Bx*T0)*T0 - Cx;
    const float d2y = (Dy + By*T1)*T1 - Cy, d2x = (Dx + Bx*T1)*T1 - Cx;
    const float q1 = d1y*d1y + d1x*d1x;
    const float q2 = d2y*d2y + d2x*d2x;
    const float dist = __builtin_amdgcn_sqrtf(fminf(q1, q2));

    const float sarg = (lw4.z - dist) * lw4.y;
    const float e = __builtin_amdgcn_exp2f(sarg * -1.4426950408889634f);
    return lw4.x * __builtin_amdgcn_rcpf(1.0f + e);
}

// 512 blocks x 512 threads; block = 32x16 px (inside one 64x64 tile), 8 waves
// = 8 8x8 quadrants (4 across x 2 down). Halves device-wide staging vs r17.
// Filter: ref-exact tile flag && ebox(E=2.45) && 8-seg divide-free band.
__global__ __launch_bounds__(512) void spline_render(
    const float* __restrict__ ga, const float* __restrict__ gb,
    const float* __restrict__ gc, const float* __restrict__ glw,
    const float* __restrict__ glc, float* __restrict__ out)
{
    __shared__ float4 s_f0[NSPL], s_f1[NSPL], s_f2[NSPL], s_eb[NSPL];
    __shared__ float4 s_lw[NSPL];
    __shared__ float  s_py9[9][NSPL], s_px9[9][NSPL];
    __shared__ float  s_R2[NSPL];
    __shared__ int    s_wl[8][NSPL];

    const int t  = threadIdx.x;
    const int bx = blockIdx.x & 15;   // 16 blocks across (32 px each)
    const int by = blockIdx.x >> 4;   // 32 blocks down  (16 px each)
    const float ty0 = (float)((by >> 2) << 6);   // enclosing 64x64 tile
    const float tx0 = (float)((bx >> 1) << 6);

    if (t < NSPL) {
        // ---- round-4 mask + constants, verbatim values ----
        const int n = t;
        const float ay  = ga[2*n],  ax  = ga[2*n+1];
        const float by_ = gb[2*n],  bx_ = gb[2*n+1];
        const float cy  = gc[2*n],  cx  = gc[2*n+1];
        const float w   = glw[n];

        float miy = fminf(ay, cy), may = fmaxf(ay, cy);
        float mix = fminf(ax, cx), maxx = fmaxf(ax, cx);
        bool cond = (by_ < miy) || (by_ > may) || (bx_ < mix) || (bx_ > maxx);
        float dny = ay - 2.0f*by_ + cy;
        float dnx = ax - 2.0f*bx_ + cx;
        bool dok = (fabsf(dny) > 1e-9f) && (fabsf(dnx) > 1e-9f);
        float tty = fminf(fmaxf((ay - by_) / ((fabsf(dny) > 1e-9f) ? dny : 1e-9f), 0.0f), 1.0f);
        float ttx = fminf(fmaxf((ax - bx_) / ((fabsf(dnx) > 1e-9f) ? dnx : 1e-9f), 0.0f), 1.0f);
        float sy = 1.0f - tty, sx = 1.0f - ttx;
        float qqy = sy*sy*ay + 2.0f*sy*tty*by_ + tty*tty*cy;
        float qqx = sx*sx*ax + 2.0f*sx*ttx*bx_ + ttx*ttx*cx;
        if (cond && dok) {
            miy = fminf(miy, qqy); may = fmaxf(may, qqy);
            mix = fminf(mix, qqx); maxx = fmaxf(maxx, qqx);
        }
        float mg = floorf(3.0f * w);   // MARGIN = 0
        float mi_py = fminf(fmaxf(floorf(miy*SCALE) - mg, 0.0f), 512.0f);
        float ma_py = fminf(fmaxf(ceilf (may*SCALE) + mg, 0.0f), 512.0f);
        float mi_px = fminf(fmaxf(floorf(mix*SCALE) - mg, 0.0f), 512.0f);
        float ma_px = fminf(fmaxf(ceilf (maxx*SCALE) + mg, 0.0f), 512.0f);
        bool flag = (ma_py > ty0) && (mi_py < ty0 + 64.0f)
                 && (ma_px > tx0) && (mi_px < tx0 + 64.0f);

        float bby = by_ + 1e-5f, bbx = bx_ + 1e-5f;
        float Ay = bby - ay, Ax = bbx - ax;
        float By = cy - bby - Ay, Bx = cx - bbx - Ax;
        float BdB = By*By + Bx*Bx;
        float nB  = -BdB;
        float AdB = Ay*By + Ax*Bx;
        float ca  = (-3.0f * AdB) / nB;
        float ax2 = ca * ca;
        s_f0[n] = make_float4(ay, ax, Ay, Ax);
        s_f1[n] = make_float4(By, Bx, ca / 27.0f, ca / 3.0f);
        s_f2[n] = make_float4(2.0f * ax2, ax2 / 3.0f,
                              2.0f * (Ay*Ay + Ax*Ax), 1.0f / nB);
        s_lw[n] = make_float4(glc[n], 6.0f / w, w, 0.0f);

        // expanded bbox, E = 2.45 band (r16-proven: dropped < 1.7e-4 each)
        float E = fmaf(2.45f * 512.0f, w, 3.0f);
        s_eb[n] = flag ? make_float4(mi_py - E, ma_py + E, mi_px - E, ma_px + E)
                       : make_float4(1e30f, -1e30f, 1e30f, -1e30f);

        // 8-segment polyline: curve(t)=a+2At+Bt^2 at t=k/8, px coords (x511).
        #pragma unroll
        for (int k = 0; k <= 8; ++k) {
            const float tk = (float)k * 0.125f;
            s_py9[k][n] = fmaf(fmaf(By, tk, Ay + Ay), tk, ay) * 511.0f;
            s_px9[k][n] = fmaf(fmaf(Bx, tk, Ax + Ax), tk, ax) * 511.0f;
        }
        float dev = __builtin_amdgcn_sqrtf(BdB) * (511.0f / 256.0f);
        float R = E + dev + 5.0f;   // halfdiag(4.95) + slop
        s_R2[n] = R * R;
    }
    __syncthreads();

    // ---- per-wave 8x8-quadrant filter (ascending, order-preserving) ----
    const int lane = t & 63;
    const int wv   = t >> 6;                    // 0..7: 4 across x 2 down
    const int wx0 = (bx << 5) + ((wv & 3) << 3);
    const int wy0 = (by << 4) + ((wv >> 2) << 3);
    const float wy0f = (float)wy0, wx0f = (float)wx0;
    const float cyp = wy0f + 3.5f, cxp = wx0f + 3.5f;   // region center (px)

    int cnt = 0;
    #pragma unroll
    for (int h = 0; h < 2; ++h) {
        const int n = (h << 6) + lane;
        const float4 eb = s_eb[n];
        bool keep = (eb.y > wy0f) && (eb.x < wy0f + 8.0f)
                 && (eb.w > wx0f) && (eb.z < wx0f + 8.0f);
        if (keep) {
            // divide-free point-to-polyline <= R test (8 segments)
            const float R2 = s_R2[n];
            float p0y = s_py9[0][n], p0x = s_px9[0][n];
            float wy = cyp - p0y, wx = cxp - p0x;
            float ww = wy*wy + wx*wx;
            bool inside = false;
            #pragma unroll
            for (int s = 1; s <= 8; ++s) {
                const float p1y = s_py9[s][n], p1x = s_px9[s][n];
                const float vy = p1y - p0y, vx = p1x - p0x;
                const float w1y = wy - vy,  w1x = wx - vx;
                const float vv = vy*vy + vx*vx;
                const float wvd = wy*vy + wx*vx;
                const float w1w1 = w1y*w1y + w1x*w1x;
                const bool in_s = (wvd <= 0.0f) ? (ww <= R2)
                               : (wvd >= vv)   ? (w1w1 <= R2)
                               : (fmaf(ww, vv, -wvd*wvd) <= R2 * vv);
                inside = inside || in_s;
                p0y = p1y; p0x = p1x;
                wy = w1y; wx = w1x; ww = w1w1;
            }
            keep = inside;
        }
        const unsigned long long b = __ballot(keep);
        const int pos = cnt + __popcll(b & ((1ull << lane) - 1ull));
        if (keep) s_wl[wv][pos] = n;
        cnt += __popcll(b);
    }

    // ---- per-pixel evaluation, unroll-3 (independent chains; same sum order) ----
    const int px_i = wx0 + (lane & 7);
    const int py_i = wy0 + (lane >> 3);
    const float py = (float)py_i * (1.0f / 511.0f);
    const float px = (float)px_i * (1.0f / 511.0f);

    float sum = 0.0f;
    int i = 0;
    for (; i + 3 <= cnt; i += 3) {
        const int n0 = s_wl[wv][i];
        const int n1 = s_wl[wv][i+1];
        const int n2 = s_wl[wv][i+2];
        const float c_0 = eval_one(py, px, s_f0[n0], s_f1[n0], s_f2[n0], s_lw[n0]);
        const float c_1 = eval_one(py, px, s_f0[n1], s_f1[n1], s_f2[n1], s_lw[n1]);
        const float c_2 = eval_one(py, px, s_f0[n2], s_f1[n2], s_f2[n2], s_lw[n2]);
        sum = ((sum + c_0) + c_1) + c_2;     // ascending order preserved
    }
    for (; i < cnt; ++i) {
        const int n0 = s_wl[wv][i];
        sum += eval_one(py, px, s_f0[n0], s_f1[n0], s_f2[n0], s_lw[n0]);
    }

    out[py_i * 512 + px_i] = 1.0f - sum;
}

extern "C" void kernel_launch(void* const* d_in, const int* in_sizes, int n_in,
                              void* d_out, int out_size, void* d_ws, size_t ws_size,
                              hipStream_t stream) {
    const float* a  = (const float*)d_in[0];
    const float* b  = (const float*)d_in[1];
    const float* c  = (const float*)d_in[2];
    const float* lw = (const float*)d_in[3];
    const float* lc = (const float*)d_in[4];
    float* out = (float*)d_out;
    spline_render<<<dim3(512), dim3(512), 0, stream>>>(a, b, c, lw, lc, out);
}

// Round 19
// 19.794 us; speedup vs baseline: 1.0889x; 1.0889x over previous
//
#include <hip/hip_runtime.h>
#include <math.h>

#define NSPL 128
#define SCALE 512.0f

__device__ __forceinline__ float fast_cbrt_pos(float x) {
    // x >= 0. Bit-hack seed (no log/exp) + 2 rcp-Newton steps; rel err ~1e-5.
    unsigned int i = __float_as_uint(x);
    i = 0x2a510680u + (unsigned int)(((unsigned long long)i * 0xAAAAAAABull) >> 33);
    float r = __uint_as_float(i);
    float r2 = r * r;
    r = fmaf(0.66666667f, r, 0.33333333f * x * __builtin_amdgcn_rcpf(r2));
    r2 = r * r;
    r = fmaf(0.66666667f, r, 0.33333333f * x * __builtin_amdgcn_rcpf(r2));
    return (x < 1e-35f) ? 0.0f : r;
}

// Hastings deg-7 acos (abs err ~2e-8). Input is EXACT (true divide + libm
// sqrt) -> no input-side amplification (r2 post-mortem). r18-proven:
// bit-identical absmax vs libm acosf.
__device__ __forceinline__ float fast_acos(float x) {
    float ax = fabsf(x);
    float p = -0.0012624911f;
    p = fmaf(p, ax, 0.0066700901f);
    p = fmaf(p, ax, -0.0170881256f);
    p = fmaf(p, ax, 0.0308918810f);
    p = fmaf(p, ax, -0.0501743046f);
    p = fmaf(p, ax, 0.0889789874f);
    p = fmaf(p, ax, -0.2145988016f);
    p = fmaf(p, ax, 1.5707963050f);
    float s = __builtin_amdgcn_sqrtf(1.0f - ax);
    float r = s * p;
    return (x >= 0.0f) ? r : (3.14159265358979323846f - r);
}

// cos/sin on [0, pi/3] via Taylor-Horner (abs err <= 4e-8). r13-proven.
__device__ __forceinline__ float cos_small(float v) {
    const float v2 = v * v;
    float p = -2.7557319e-7f;
    p = fmaf(p, v2, 2.4801587e-5f);
    p = fmaf(p, v2, -1.3888889e-3f);
    p = fmaf(p, v2, 4.1666667e-2f);
    p = fmaf(p, v2, -0.5f);
    return fmaf(p, v2, 1.0f);
}
__device__ __forceinline__ float sin_small(float v) {
    const float v2 = v * v;
    float p = 2.7557319e-6f;
    p = fmaf(p, v2, -1.9841270e-4f);
    p = fmaf(p, v2, 8.3333333e-3f);
    p = fmaf(p, v2, -0.16666667f);
    return v * fmaf(p, v2, 1.0f);
}

// One kept-spline contribution for one pixel (r17 numerics + poly acos).
__device__ __forceinline__ float eval_one(
    float py, float px, const float4 f0, const float4 f1,
    const float4 f2, const float4 lw4)
{
    const float Ay = f0.z, Ax = f0.w;
    const float By = f1.x, Bx = f1.y;
    const float ca27 = f1.z, ca3 = f1.w;
    const float twoax2 = f2.x, third = f2.y, cbK = f2.z, r_nB = f2.w;

    const float Cy = py - f0.x, Cx = px - f0.y;
    const float CdB = Cy*By + Cx*Bx;
    const float CdA = Cy*Ay + Cx*Ax;
    const float cb = (CdB - cbK) * r_nB;
    const float cc = CdA * r_nB;

    const float p_  = cb - third;
    const float p3  = p_ * p_ * p_;
    const float q   = fmaf(ca27, fmaf(-9.0f, cb, twoax2), cc);
    const float d   = fmaf(q, q, p3 * (4.0f/27.0f));

    const bool sgl = d > 0.0f;
    // single-root via Cardano identity (r12-proven)
    const float sd = __builtin_amdgcn_sqrtf(fmaxf(d, 0.0f));
    const float mm = (fabsf(q) + sd) * 0.5f;
    const float r  = fast_cbrt_pos(mm);
    const float sg = (q > 0.0f) ? -1.0f : 1.0f;
    const float r0 = fmaf(sg, fmaf(-p_ * 0.33333334f, __builtin_amdgcn_rcpf(r), r), -ca3);

    float T0 = r0, T1 = r0;
    const unsigned long long bd = __ballot(sgl);
    if (bd != ~0ull) {  // trig branch: exact aarg (true div + libm sqrt)
        const float p3s = (fabsf(p3) > 1e-9f) ? p3 : 1e-9f;
        const float aarg = -sqrtf(fmaxf(-27.0f / p3s, 0.0f)) * q * 0.5f;
        const float v = fast_acos(fminf(fmaxf(aarg, -1.0f), 1.0f)) * (1.0f/3.0f);
        const float m = cos_small(v);
        const float nn = sin_small(v) * 1.7320508075688772f;
        const float sp = sqrtf(fmaxf(-p_ / 3.0f, 0.0f));
        const float r1 = (m + m) * sp - ca3;
        const float r2 = (-nn - m) * sp - ca3;
        if (!sgl) { T0 = r1; T1 = r2; }
    }
    T0 = fminf(fmaxf(T0, 0.0f), 1.0f);
    T1 = fminf(fmaxf(T1, 0.0f), 1.0f);

    const float Dy = Ay + Ay, Dx = Ax + Ax;
    const float d1y = (Dy + By*T0)*T0 - Cy, d1x = (Dx + Bx*T0)*T0 - Cx;
    const float d2y = (Dy + By*T1)*T1 - Cy, d2x = (Dx + Bx*T1)*T1 - Cx;
    const float q1 = d1y*d1y + d1x*d1x;
    const float q2 = d2y*d2y + d2x*d2x;
    const float dist = __builtin_amdgcn_sqrtf(fminf(q1, q2));

    const float sarg = (lw4.z - dist) * lw4.y;
    const float e = __builtin_amdgcn_exp2f(sarg * -1.4426950408889634f);
    return lw4.x * __builtin_amdgcn_rcpf(1.0f + e);
}

// r17 structure (proven best, 20.59 us): 1024 blocks x 256 threads; block =
// 16x16 px, wave = 8x8 quadrant. Filter: ref-exact tile flag && ebox(E=2.45)
// && 8-segment divide-free chord-band. Eval: unroll-3, ascending sum order.
__global__ __launch_bounds__(256) void spline_render(
    const float* __restrict__ ga, const float* __restrict__ gb,
    const float* __restrict__ gc, const float* __restrict__ glw,
    const float* __restrict__ glc, float* __restrict__ out)
{
    __shared__ float4 s_f0[NSPL], s_f1[NSPL], s_f2[NSPL], s_eb[NSPL];
    __shared__ float4 s_lw[NSPL];
    __shared__ float  s_py9[9][NSPL], s_px9[9][NSPL];
    __shared__ float  s_R2[NSPL];
    __shared__ int    s_wl[4][NSPL];

    const int t  = threadIdx.x;
    const int bx = blockIdx.x & 31;   // 32 blocks across (16 px each)
    const int by = blockIdx.x >> 5;   // 32 blocks down  (16 px each)
    const float ty0 = (float)((by >> 2) << 6);   // enclosing 64x64 tile
    const float tx0 = (float)((bx >> 2) << 6);

    if (t < NSPL) {
        // ---- round-4 mask + constants, verbatim values ----
        const int n = t;
        const float ay  = ga[2*n],  ax  = ga[2*n+1];
        const float by_ = gb[2*n],  bx_ = gb[2*n+1];
        const float cy  = gc[2*n],  cx  = gc[2*n+1];
        const float w   = glw[n];

        float miy = fminf(ay, cy), may = fmaxf(ay, cy);
        float mix = fminf(ax, cx), maxx = fmaxf(ax, cx);
        bool cond = (by_ < miy) || (by_ > may) || (bx_ < mix) || (bx_ > maxx);
        float dny = ay - 2.0f*by_ + cy;
        float dnx = ax - 2.0f*bx_ + cx;
        bool dok = (fabsf(dny) > 1e-9f) && (fabsf(dnx) > 1e-9f);
        float tty = fminf(fmaxf((ay - by_) / ((fabsf(dny) > 1e-9f) ? dny : 1e-9f), 0.0f), 1.0f);
        float ttx = fminf(fmaxf((ax - bx_) / ((fabsf(dnx) > 1e-9f) ? dnx : 1e-9f), 0.0f), 1.0f);
        float sy = 1.0f - tty, sx = 1.0f - ttx;
        float qqy = sy*sy*ay + 2.0f*sy*tty*by_ + tty*tty*cy;
        float qqx = sx*sx*ax + 2.0f*sx*ttx*bx_ + ttx*ttx*cx;
        if (cond && dok) {
            miy = fminf(miy, qqy); may = fmaxf(may, qqy);
            mix = fminf(mix, qqx); maxx = fmaxf(maxx, qqx);
        }
        float mg = floorf(3.0f * w);   // MARGIN = 0
        float mi_py = fminf(fmaxf(floorf(miy*SCALE) - mg, 0.0f), 512.0f);
        float ma_py = fminf(fmaxf(ceilf (may*SCALE) + mg, 0.0f), 512.0f);
        float mi_px = fminf(fmaxf(floorf(mix*SCALE) - mg, 0.0f), 512.0f);
        float ma_px = fminf(fmaxf(ceilf (maxx*SCALE) + mg, 0.0f), 512.0f);
        bool flag = (ma_py > ty0) && (mi_py < ty0 + 64.0f)
                 && (ma_px > tx0) && (mi_px < tx0 + 64.0f);

        float bby = by_ + 1e-5f, bbx = bx_ + 1e-5f;
        float Ay = bby - ay, Ax = bbx - ax;
        float By = cy - bby - Ay, Bx = cx - bbx - Ax;
        float BdB = By*By + Bx*Bx;
        float nB  = -BdB;
        float AdB = Ay*By + Ax*Bx;
        float ca  = (-3.0f * AdB) / nB;
        float ax2 = ca * ca;
        s_f0[n] = make_float4(ay, ax, Ay, Ax);
        s_f1[n] = make_float4(By, Bx, ca / 27.0f, ca / 3.0f);
        s_f2[n] = make_float4(2.0f * ax2, ax2 / 3.0f,
                              2.0f * (Ay*Ay + Ax*Ax), 1.0f / nB);
        s_lw[n] = make_float4(glc[n], 6.0f / w, w, 0.0f);

        // expanded bbox, E = 2.45 band (r16-proven: dropped < 1.7e-4 each)
        float E = fmaf(2.45f * 512.0f, w, 3.0f);
        s_eb[n] = flag ? make_float4(mi_py - E, ma_py + E, mi_px - E, ma_px + E)
                       : make_float4(1e30f, -1e30f, 1e30f, -1e30f);

        // 8-segment polyline: curve(t)=a+2At+Bt^2 at t=k/8, px coords (x511).
        #pragma unroll
        for (int k = 0; k <= 8; ++k) {
            const float tk = (float)k * 0.125f;
            s_py9[k][n] = fmaf(fmaf(By, tk, Ay + Ay), tk, ay) * 511.0f;
            s_px9[k][n] = fmaf(fmaf(Bx, tk, Ax + Ax), tk, ax) * 511.0f;
        }
        float dev = __builtin_amdgcn_sqrtf(BdB) * (511.0f / 256.0f);
        float R = E + dev + 5.0f;   // halfdiag(4.95) + slop
        s_R2[n] = R * R;
    }
    __syncthreads();

    // ---- per-wave 8x8-quadrant filter (ascending, order-preserving) ----
    const int lane = t & 63;
    const int wv   = t >> 6;
    const int wx0 = (bx << 4) + ((wv & 1) << 3);
    const int wy0 = (by << 4) + ((wv >> 1) << 3);
    const float wy0f = (float)wy0, wx0f = (float)wx0;
    const float cyp = wy0f + 3.5f, cxp = wx0f + 3.5f;   // region center (px)

    int cnt = 0;
    #pragma unroll
    for (int h = 0; h < 2; ++h) {
        const int n = (h << 6) + lane;
        const float4 eb = s_eb[n];
        bool keep = (eb.y > wy0f) && (eb.x < wy0f + 8.0f)
                 && (eb.w > wx0f) && (eb.z < wx0f + 8.0f);
        if (keep) {
            // divide-free point-to-polyline <= R test (8 segments)
            const float R2 = s_R2[n];
            float p0y = s_py9[0][n], p0x = s_px9[0][n];
            float wy = cyp - p0y, wx = cxp - p0x;
            float ww = wy*wy + wx*wx;
            bool inside = false;
            #pragma unroll
            for (int s = 1; s <= 8; ++s) {
                const float p1y = s_py9[s][n], p1x = s_px9[s][n];
                const float vy = p1y - p0y, vx = p1x - p0x;
                const float w1y = wy - vy,  w1x = wx - vx;
                const float vv = vy*vy + vx*vx;
                const float wvd = wy*vy + wx*vx;
                const float w1w1 = w1y*w1y + w1x*w1x;
                const bool in_s = (wvd <= 0.0f) ? (ww <= R2)
                               : (wvd >= vv)   ? (w1w1 <= R2)
                               : (fmaf(ww, vv, -wvd*wvd) <= R2 * vv);
                inside = inside || in_s;
                p0y = p1y; p0x = p1x;
                wy = w1y; wx = w1x; ww = w1w1;
            }
            keep = inside;
        }
        const unsigned long long b = __ballot(keep);
        const int pos = cnt + __popcll(b & ((1ull << lane) - 1ull));
        if (keep) s_wl[wv][pos] = n;
        cnt += __popcll(b);
    }

    // ---- per-pixel evaluation, unroll-3 (independent chains; same sum order) ----
    const int px_i = wx0 + (lane & 7);
    const int py_i = wy0 + (lane >> 3);
    const float py = (float)py_i * (1.0f / 511.0f);
    const float px = (float)px_i * (1.0f / 511.0f);

    float sum = 0.0f;
    int i = 0;
    for (; i + 3 <= cnt; i += 3) {
        const int n0 = s_wl[wv][i];
        const int n1 = s_wl[wv][i+1];
        const int n2 = s_wl[wv][i+2];
        const float c_0 = eval_one(py, px, s_f0[n0], s_f1[n0], s_f2[n0], s_lw[n0]);
        const float c_1 = eval_one(py, px, s_f0[n1], s_f1[n1], s_f2[n1], s_lw[n1]);
        const float c_2 = eval_one(py, px, s_f0[n2], s_f1[n2], s_f2[n2], s_lw[n2]);
        sum = ((sum + c_0) + c_1) + c_2;     // ascending order preserved
    }
    for (; i < cnt; ++i) {
        const int n0 = s_wl[wv][i];
        sum += eval_one(py, px, s_f0[n0], s_f1[n0], s_f2[n0], s_lw[n0]);
    }

    out[py_i * 512 + px_i] = 1.0f - sum;
}

extern "C" void kernel_launch(void* const* d_in, const int* in_sizes, int n_in,
                              void* d_out, int out_size, void* d_ws, size_t ws_size,
                              hipStream_t stream) {
    const float* a  = (const float*)d_in[0];
    const float* b  = (const float*)d_in[1];
    const float* c  = (const float*)d_in[2];
    const float* lw = (const float*)d_in[3];
    const float* lc = (const float*)d_in[4];
    float* out = (float*)d_out;
    spline_render<<<dim3(1024), dim3(256), 0, stream>>>(a, b, c, lw, lc, out);
}